// Round 1
// baseline (172.966 us; speedup 1.0000x reference)
//
#include <hip/hip_runtime.h>
#include <hip/hip_bf16.h>
#include <stdint.h>

// Problem constants
#define B_    4
#define CQ_   256
#define CKV_  256
#define NQ_   2048
#define NKV_  2048
#define H_    8
#define DK_   64
#define HD_   512   // H_*DK_

typedef __attribute__((ext_vector_type(8))) short bf16x8;
typedef __attribute__((ext_vector_type(4))) float f32x4;

__device__ __forceinline__ short f2bf(float f) {
    unsigned u = __builtin_bit_cast(unsigned, f);
    u = (u + 0x7FFFu + ((u >> 16) & 1u)) >> 16;   // RNE truncate to bf16
    return (short)u;
}

// -------------------------------------------------------------------------
// Kernel 1: K/V projection.  Per b: C[n][o] = sum_c x_kv[b][c][n] * W[o][c]
// W = Wk for o<512 (block-uniform: bx<4), Wv otherwise.
// Output: Kbuf/Vbuf bf16, layout [b][n][o_local] (n-major, 512 per row).
// MFMA mapping: M=n, N=o, K=c.  Block tile 64(n) x 128(o), 4 waves 2x2.
// -------------------------------------------------------------------------
__global__ __launch_bounds__(256) void proj_kv_kernel(
    const float* __restrict__ x_kv,
    const float* __restrict__ Wk,
    const float* __restrict__ Wv,
    unsigned short* __restrict__ Kbuf,
    unsigned short* __restrict__ Vbuf)
{
    const int bx   = blockIdx.x;          // 0..7 ; 0-3 -> K, 4-7 -> V
    const int nblk = blockIdx.y * 64;     // 0..31
    const int b    = blockIdx.z;          // 0..3
    const int tid  = threadIdx.x;
    const int w    = tid >> 6;
    const int L    = tid & 63;
    const int row16 = L & 15;
    const int quad  = L >> 4;
    const int wn = (w >> 1) * 32;         // wave n offset within block
    const int wo = (w & 1) * 64;          // wave o offset within block

    const bool isK = (bx < 4);
    const float* W = isK ? Wk : Wv;
    unsigned short* Obuf = isK ? Kbuf : Vbuf;
    const int olocal_base = (bx & 3) * 128 + wo;   // within [0,512)

    const float* Xb = x_kv + (size_t)b * CKV_ * NKV_;

    f32x4 acc[2][4];
#pragma unroll
    for (int mi = 0; mi < 2; ++mi)
#pragma unroll
        for (int ni = 0; ni < 4; ++ni) acc[mi][ni] = (f32x4){0.f,0.f,0.f,0.f};

    for (int kk = 0; kk < 8; ++kk) {
        const int c0 = kk * 32 + quad * 8;  // this lane's 8 k-values: c0..c0+7

        bf16x8 afrag[2];
#pragma unroll
        for (int mi = 0; mi < 2; ++mi) {
            const int n = nblk + wn + mi * 16 + row16;
            const float* xp = Xb + (size_t)c0 * NKV_ + n;
#pragma unroll
            for (int j = 0; j < 8; ++j) afrag[mi][j] = f2bf(xp[(size_t)j * NKV_]);
        }

        bf16x8 bfrag[4];
#pragma unroll
        for (int ni = 0; ni < 4; ++ni) {
            const int o = olocal_base + ni * 16 + row16;
            const f32x4* wp = (const f32x4*)(W + (size_t)o * CKV_ + c0);
            f32x4 w0 = wp[0], w1 = wp[1];
            bfrag[ni][0] = f2bf(w0.x); bfrag[ni][1] = f2bf(w0.y);
            bfrag[ni][2] = f2bf(w0.z); bfrag[ni][3] = f2bf(w0.w);
            bfrag[ni][4] = f2bf(w1.x); bfrag[ni][5] = f2bf(w1.y);
            bfrag[ni][6] = f2bf(w1.z); bfrag[ni][7] = f2bf(w1.w);
        }

#pragma unroll
        for (int mi = 0; mi < 2; ++mi)
#pragma unroll
            for (int ni = 0; ni < 4; ++ni)
                acc[mi][ni] = __builtin_amdgcn_mfma_f32_16x16x32_bf16(
                    afrag[mi], bfrag[ni], acc[mi][ni], 0, 0, 0);
    }

#pragma unroll
    for (int mi = 0; mi < 2; ++mi) {
#pragma unroll
        for (int ni = 0; ni < 4; ++ni) {
#pragma unroll
            for (int r = 0; r < 4; ++r) {
                const int n  = nblk + wn + mi * 16 + quad * 4 + r;
                const int ol = olocal_base + ni * 16 + row16;
                Obuf[((size_t)b * NKV_ + n) * HD_ + ol] =
                    (unsigned short)f2bf(acc[mi][ni][r]);
            }
        }
    }
}

// -------------------------------------------------------------------------
// Kernel 2: S partials.  S[b,h][d'][d] = sum_n K[b][n][h*64+d'] * V[b][n][h*64+d]
// split-K over n: 8 chunks of 256.  One block per (chunk,h,b): 64x64 output.
// MFMA mapping: M=d', N=d, K=n.  4 waves, each a 16(d') x 64(d) strip.
// -------------------------------------------------------------------------
__global__ __launch_bounds__(256) void attn_s_kernel(
    const unsigned short* __restrict__ Kbuf,
    const unsigned short* __restrict__ Vbuf,
    float* __restrict__ Spart)
{
    const int chunk = blockIdx.x;   // 0..7
    const int h     = blockIdx.y;   // 0..7
    const int b     = blockIdx.z;   // 0..3
    const int tid   = threadIdx.x;
    const int w     = tid >> 6;
    const int L     = tid & 63;
    const int row16 = L & 15;
    const int quad  = L >> 4;
    const int n0    = chunk * 256;

    const unsigned short* Kb = Kbuf + ((size_t)b * NKV_) * HD_ + h * DK_;
    const unsigned short* Vb = Vbuf + ((size_t)b * NKV_) * HD_ + h * DK_;

    f32x4 acc[4];
#pragma unroll
    for (int ni = 0; ni < 4; ++ni) acc[ni] = (f32x4){0.f,0.f,0.f,0.f};

    for (int it = 0; it < 8; ++it) {
        const int nbase = n0 + it * 32 + quad * 8;

        bf16x8 a;
        {
            const unsigned short* kp = Kb + (size_t)nbase * HD_ + w * 16 + row16;
#pragma unroll
            for (int j = 0; j < 8; ++j) a[j] = (short)kp[(size_t)j * HD_];
        }
        bf16x8 bfrag[4];
#pragma unroll
        for (int ni = 0; ni < 4; ++ni) {
            const unsigned short* vp = Vb + (size_t)nbase * HD_ + ni * 16 + row16;
#pragma unroll
            for (int j = 0; j < 8; ++j) bfrag[ni][j] = (short)vp[(size_t)j * HD_];
        }
#pragma unroll
        for (int ni = 0; ni < 4; ++ni)
            acc[ni] = __builtin_amdgcn_mfma_f32_16x16x32_bf16(a, bfrag[ni], acc[ni], 0, 0, 0);
    }

    const int bh = b * H_ + h;
    float* Sp = Spart + ((size_t)chunk * 32 + bh) * 4096;
#pragma unroll
    for (int ni = 0; ni < 4; ++ni) {
#pragma unroll
        for (int r = 0; r < 4; ++r) {
            const int dp = w * 16 + quad * 4 + r;  // d'
            const int d  = ni * 16 + row16;
            Sp[dp * 64 + d] = acc[ni][r];
        }
    }
}

// -------------------------------------------------------------------------
// Kernel 3: R[b][c][h*64+d'] = (1/64) * sum_d Wo[c][h*64+d] * S[b,h][d'][d]
// One block per (h,b).  Sums the 8 split-K partials first.
// -------------------------------------------------------------------------
__global__ __launch_bounds__(256) void fold_r_kernel(
    const float* __restrict__ Spart,
    const float* __restrict__ Wo,
    float* __restrict__ Rbuf)
{
    const int h = blockIdx.x;   // 0..7
    const int b = blockIdx.y;   // 0..3
    const int bh = b * H_ + h;
    const int tid = threadIdx.x;

    __shared__ float Ssum[4096];
    for (int idx = tid; idx < 4096; idx += 256) {
        float s = 0.f;
#pragma unroll
        for (int slot = 0; slot < 8; ++slot)
            s += Spart[((size_t)slot * 32 + bh) * 4096 + idx];
        Ssum[idx] = s * (1.0f / 64.0f);
    }
    __syncthreads();

    const int c = tid;   // 0..255
    float wrow[64];
    const float* wp = Wo + (size_t)c * HD_ + h * DK_;
#pragma unroll
    for (int d = 0; d < 64; ++d) wrow[d] = wp[d];

    float* rp = Rbuf + ((size_t)b * CQ_ + c) * HD_ + h * DK_;
    for (int dp = 0; dp < 64; ++dp) {
        float a = 0.f;
#pragma unroll
        for (int d = 0; d < 64; ++d) a += wrow[d] * Ssum[dp * 64 + d];
        rp[dp] = a;
    }
}

// -------------------------------------------------------------------------
// Kernel 4: N[b] = R[b] @ Wq   (256x512)@(512x256), fp32 tiled 32x32.
// -------------------------------------------------------------------------
__global__ __launch_bounds__(256) void fold_n_kernel(
    const float* __restrict__ Rbuf,
    const float* __restrict__ Wq,
    float* __restrict__ Nbuf)
{
    const int cqb = blockIdx.x * 32;
    const int cb  = blockIdx.y * 32;
    const int b   = blockIdx.z;
    const int tid = threadIdx.x;
    const int tx = tid & 15, ty = tid >> 4;

    __shared__ float Rt[32][33];
    __shared__ float Wt[32][33];

    float a00 = 0.f, a01 = 0.f, a10 = 0.f, a11 = 0.f;
    for (int ko = 0; ko < HD_; ko += 32) {
#pragma unroll
        for (int i = 0; i < 4; ++i) {
            const int lin = tid + i * 256;
            const int rr = lin >> 5, cc = lin & 31;
            Rt[rr][cc] = Rbuf[((size_t)b * CQ_ + cb + rr) * HD_ + ko + cc];
            Wt[rr][cc] = Wq[(size_t)(ko + rr) * CQ_ + cqb + cc];
        }
        __syncthreads();
#pragma unroll
        for (int k = 0; k < 32; ++k) {
            const float r0 = Rt[ty * 2][k],     r1 = Rt[ty * 2 + 1][k];
            const float w0 = Wt[k][tx * 2],     w1 = Wt[k][tx * 2 + 1];
            a00 += r0 * w0; a01 += r0 * w1; a10 += r1 * w0; a11 += r1 * w1;
        }
        __syncthreads();
    }
    float* np = Nbuf + ((size_t)b * CQ_ + cb + ty * 2) * CQ_ + cqb + tx * 2;
    np[0] = a00; np[1] = a01; np[CQ_] = a10; np[CQ_ + 1] = a11;
}

// -------------------------------------------------------------------------
// Kernel 5: out[b][c][n] = gamma * sum_cq N[b][c][cq]*x_q[b][cq][n] + x_q[b][c][n]
// MFMA mapping: M=c, N=n, K=cq.  Block tile 64(c) x 128(n), 4 waves 2x2.
// -------------------------------------------------------------------------
__global__ __launch_bounds__(256) void final_kernel(
    const float* __restrict__ Nbuf,
    const float* __restrict__ x_q,
    const float* __restrict__ gamma,
    float* __restrict__ out)
{
    const int nblk = blockIdx.x * 128;   // 0..15
    const int cblk = blockIdx.y * 64;    // 0..3
    const int b    = blockIdx.z;
    const int tid  = threadIdx.x;
    const int w    = tid >> 6;
    const int L    = tid & 63;
    const int row16 = L & 15;
    const int quad  = L >> 4;
    const int wc = (w >> 1) * 32;
    const int wn = (w & 1) * 64;

    const float* Nb = Nbuf + (size_t)b * CQ_ * CQ_;
    const float* Xb = x_q + (size_t)b * CQ_ * NQ_;
    const float g = gamma[0];

    f32x4 acc[2][4];
#pragma unroll
    for (int mi = 0; mi < 2; ++mi)
#pragma unroll
        for (int ni = 0; ni < 4; ++ni) acc[mi][ni] = (f32x4){0.f,0.f,0.f,0.f};

    for (int kk = 0; kk < 8; ++kk) {
        const int c0 = kk * 32 + quad * 8;

        bf16x8 afrag[2];
#pragma unroll
        for (int mi = 0; mi < 2; ++mi) {
            const int c = cblk + wc + mi * 16 + row16;
            const f32x4* np = (const f32x4*)(Nb + (size_t)c * CQ_ + c0);
            f32x4 n0 = np[0], n1 = np[1];
            afrag[mi][0] = f2bf(n0.x); afrag[mi][1] = f2bf(n0.y);
            afrag[mi][2] = f2bf(n0.z); afrag[mi][3] = f2bf(n0.w);
            afrag[mi][4] = f2bf(n1.x); afrag[mi][5] = f2bf(n1.y);
            afrag[mi][6] = f2bf(n1.z); afrag[mi][7] = f2bf(n1.w);
        }

        bf16x8 bfrag[4];
#pragma unroll
        for (int ni = 0; ni < 4; ++ni) {
            const int n = nblk + wn + ni * 16 + row16;
            const float* xp = Xb + (size_t)c0 * NQ_ + n;
#pragma unroll
            for (int j = 0; j < 8; ++j) bfrag[ni][j] = f2bf(xp[(size_t)j * NQ_]);
        }

#pragma unroll
        for (int mi = 0; mi < 2; ++mi)
#pragma unroll
            for (int ni = 0; ni < 4; ++ni)
                acc[mi][ni] = __builtin_amdgcn_mfma_f32_16x16x32_bf16(
                    afrag[mi], bfrag[ni], acc[mi][ni], 0, 0, 0);
    }

#pragma unroll
    for (int mi = 0; mi < 2; ++mi) {
#pragma unroll
        for (int ni = 0; ni < 4; ++ni) {
#pragma unroll
            for (int r = 0; r < 4; ++r) {
                const int c = cblk + wc + mi * 16 + quad * 4 + r;
                const int n = nblk + wn + ni * 16 + row16;
                const size_t idx = ((size_t)b * CQ_ + c) * NQ_ + n;
                out[idx] = g * acc[mi][ni][r] + Xb[(size_t)c * NQ_ + n];
            }
        }
    }
}

// -------------------------------------------------------------------------
extern "C" void kernel_launch(void* const* d_in, const int* in_sizes, int n_in,
                              void* d_out, int out_size, void* d_ws, size_t ws_size,
                              hipStream_t stream) {
    const float* x_q   = (const float*)d_in[0];
    const float* x_kv  = (const float*)d_in[1];
    const float* Wq    = (const float*)d_in[2];
    const float* Wk    = (const float*)d_in[3];
    const float* Wv    = (const float*)d_in[4];
    const float* Wo    = (const float*)d_in[5];
    const float* gamma = (const float*)d_in[6];
    float* out = (float*)d_out;

    char* ws = (char*)d_ws;
    // ws layout (bytes):
    //   Kbuf   bf16 [4][2048][512]   0        .. 8388608
    //   Vbuf   bf16 [4][2048][512]   8388608  .. 16777216
    //   Spart  f32  [8][32][64][64]  16777216 .. 20971520
    //   Rbuf   f32  [4][256][512]    20971520 .. 23068672
    //   Nbuf   f32  [4][256][256]    23068672 .. 24117248
    unsigned short* Kbuf = (unsigned short*)(ws);
    unsigned short* Vbuf = (unsigned short*)(ws + 8388608);
    float* Spart = (float*)(ws + 16777216);
    float* Rbuf  = (float*)(ws + 20971520);
    float* Nbuf  = (float*)(ws + 23068672);

    proj_kv_kernel<<<dim3(8, 32, 4), 256, 0, stream>>>(x_kv, Wk, Wv, Kbuf, Vbuf);
    attn_s_kernel<<<dim3(8, 8, 4), 256, 0, stream>>>(Kbuf, Vbuf, Spart);
    fold_r_kernel<<<dim3(8, 4), 256, 0, stream>>>(Spart, Wo, Rbuf);
    fold_n_kernel<<<dim3(8, 8, 4), 256, 0, stream>>>(Rbuf, Wq, Nbuf);
    final_kernel<<<dim3(16, 4, 4), 256, 0, stream>>>(Nbuf, x_q, gamma, out);
}

// Round 2
// 156.678 us; speedup vs baseline: 1.1040x; 1.1040x over previous
//
#include <hip/hip_runtime.h>
#include <hip/hip_bf16.h>
#include <stdint.h>

// Problem constants
#define B_    4
#define CQ_   256
#define CKV_  256
#define NQ_   2048
#define NKV_  2048
#define H_    8
#define DK_   64
#define HD_   512   // H_*DK_

typedef __attribute__((ext_vector_type(8))) short bf16x8;
typedef __attribute__((ext_vector_type(4))) float f32x4;

__device__ __forceinline__ short f2bf(float f) {
    unsigned u = __builtin_bit_cast(unsigned, f);
    u = (u + 0x7FFFu + ((u >> 16) & 1u)) >> 16;   // RNE truncate to bf16
    return (short)u;
}

// -------------------------------------------------------------------------
// Kernel 1: Gram partials.  Gpart[kc][b][c][c'] = sum_{n in chunk} x[c][n]*x[c'][n]
// Both MFMA operands have K = n (contiguous in memory) -> pure float4 loads.
// Block tile 64(c) x 128(c'), 4 waves in 2x2 (wave tile 32x64). split-K=8.
// -------------------------------------------------------------------------
__global__ __launch_bounds__(256) void gram_kernel(
    const float* __restrict__ x_kv,
    float* __restrict__ Gpart)
{
    const int kc = blockIdx.x;            // 0..7  (n-chunk of 256)
    const int t  = blockIdx.y;            // 0..7  tile: c-tile (t>>1), c'-tile (t&1)
    const int b  = blockIdx.z;            // 0..3
    const int tid = threadIdx.x;
    const int w   = tid >> 6;
    const int L   = tid & 63;
    const int r16 = L & 15;
    const int q   = L >> 4;
    const int tc  = (t >> 1) * 64;        // A rows base
    const int tcp = (t & 1) * 128;        // B rows base
    const int wm  = (w >> 1) * 32;        // wave c offset
    const int wn  = (w & 1) * 64;         // wave c' offset
    const int n0  = kc * 256;

    const float* Xb = x_kv + (size_t)b * CKV_ * NKV_;

    f32x4 acc[2][4];
#pragma unroll
    for (int mi = 0; mi < 2; ++mi)
#pragma unroll
        for (int ni = 0; ni < 4; ++ni) acc[mi][ni] = (f32x4){0.f,0.f,0.f,0.f};

    for (int kk = 0; kk < 8; ++kk) {
        const int nbase = n0 + kk * 32 + q * 8;

        bf16x8 a[2];
#pragma unroll
        for (int mi = 0; mi < 2; ++mi) {
            const int row = tc + wm + mi * 16 + r16;
            const f32x4* p = (const f32x4*)(Xb + (size_t)row * NKV_ + nbase);
            f32x4 v0 = p[0], v1 = p[1];
            a[mi][0] = f2bf(v0.x); a[mi][1] = f2bf(v0.y);
            a[mi][2] = f2bf(v0.z); a[mi][3] = f2bf(v0.w);
            a[mi][4] = f2bf(v1.x); a[mi][5] = f2bf(v1.y);
            a[mi][6] = f2bf(v1.z); a[mi][7] = f2bf(v1.w);
        }
        bf16x8 bb[4];
#pragma unroll
        for (int ni = 0; ni < 4; ++ni) {
            const int row = tcp + wn + ni * 16 + r16;
            const f32x4* p = (const f32x4*)(Xb + (size_t)row * NKV_ + nbase);
            f32x4 v0 = p[0], v1 = p[1];
            bb[ni][0] = f2bf(v0.x); bb[ni][1] = f2bf(v0.y);
            bb[ni][2] = f2bf(v0.z); bb[ni][3] = f2bf(v0.w);
            bb[ni][4] = f2bf(v1.x); bb[ni][5] = f2bf(v1.y);
            bb[ni][6] = f2bf(v1.z); bb[ni][7] = f2bf(v1.w);
        }
#pragma unroll
        for (int mi = 0; mi < 2; ++mi)
#pragma unroll
            for (int ni = 0; ni < 4; ++ni)
                acc[mi][ni] = __builtin_amdgcn_mfma_f32_16x16x32_bf16(
                    a[mi], bb[ni], acc[mi][ni], 0, 0, 0);
    }

    float* Gp = Gpart + ((size_t)kc * B_ + b) * 65536;
#pragma unroll
    for (int mi = 0; mi < 2; ++mi)
#pragma unroll
        for (int ni = 0; ni < 4; ++ni)
#pragma unroll
            for (int r = 0; r < 4; ++r) {
                const int row = tc + wm + mi * 16 + q * 4 + r;
                const int col = tcp + wn + ni * 16 + r16;
                Gp[row * 256 + col] = acc[mi][ni][r];
            }
}

// -------------------------------------------------------------------------
// Kernel 2: reduce split-K partials, scale by 1/64, convert to bf16.
// -------------------------------------------------------------------------
__global__ __launch_bounds__(256) void reduce_g_kernel(
    const float* __restrict__ Gpart,
    unsigned short* __restrict__ Gsum)
{
    const int idx4 = blockIdx.x * 256 + threadIdx.x;  // 65536 total
    const size_t base = (size_t)idx4 * 4;
    f32x4 s = (f32x4){0.f,0.f,0.f,0.f};
#pragma unroll
    for (int kc = 0; kc < 8; ++kc) {
        f32x4 v = *(const f32x4*)(Gpart + (size_t)kc * 262144 + base);
        s.x += v.x; s.y += v.y; s.z += v.z; s.w += v.w;
    }
    const float sc = 1.0f / 64.0f;
    ushort4 o;
    o.x = (unsigned short)f2bf(s.x * sc);
    o.y = (unsigned short)f2bf(s.y * sc);
    o.z = (unsigned short)f2bf(s.z * sc);
    o.w = (unsigned short)f2bf(s.w * sc);
    *(ushort4*)(Gsum + base) = o;
}

// -------------------------------------------------------------------------
// Kernel 3: fused fold. Per (b,h):
//   E[dp][c'] = sum_c  Wk[h64+dp][c]  * G[c][c']       (B-frag reads G[c'][c] row — symmetry)
//   S[dp][d]  = sum_c' E[dp][c']      * Wv[h64+d][c']
//   R[c][dp]  = sum_d  Wo[c][h64+d]   * S[dp][d]       (G already carries the 1/64)
// E in LDS as bf16 (stride 264), S in LDS fp32 (stride 68) — conflict-benign.
// -------------------------------------------------------------------------
__global__ __launch_bounds__(256) void fold_esr_kernel(
    const unsigned short* __restrict__ Gsum,   // bf16, pre-scaled by 1/64
    const float* __restrict__ Wk,
    const float* __restrict__ Wv,
    const float* __restrict__ Wo,
    float* __restrict__ Rbuf)
{
    const int h = blockIdx.x;   // 0..7
    const int b = blockIdx.y;   // 0..3
    const int tid = threadIdx.x;
    const int w   = tid >> 6;
    const int L   = tid & 63;
    const int r16 = L & 15;
    const int q   = L >> 4;

    __shared__ unsigned short E_lds[64 * 264];  // bf16, 33.8 KB
    __shared__ float S_lds[64 * 68];            // fp32, 17.4 KB

    const unsigned short* Gb = Gsum + (size_t)b * 65536;

    // ---- Phase 1: E = Wk_h * G  (M=dp 64, N=c' 256, K=c 256). wave w: dp strip w*16.
    f32x4 accE[16];
#pragma unroll
    for (int ni = 0; ni < 16; ++ni) accE[ni] = (f32x4){0.f,0.f,0.f,0.f};

    for (int kk = 0; kk < 8; ++kk) {
        const int c0 = kk * 32 + q * 8;
        bf16x8 a;
        {
            const f32x4* wp = (const f32x4*)(Wk + (size_t)(h * 64 + w * 16 + r16) * CKV_ + c0);
            f32x4 v0 = wp[0], v1 = wp[1];
            a[0] = f2bf(v0.x); a[1] = f2bf(v0.y); a[2] = f2bf(v0.z); a[3] = f2bf(v0.w);
            a[4] = f2bf(v1.x); a[5] = f2bf(v1.y); a[6] = f2bf(v1.z); a[7] = f2bf(v1.w);
        }
#pragma unroll
        for (int ni = 0; ni < 16; ++ni) {
            // B[k=c][n=c'] = G[c][c'] = G[c'][c]  (symmetric) -> row c' contiguous
            const bf16x8 bb = *(const bf16x8*)(Gb + (size_t)(ni * 16 + r16) * 256 + c0);
            accE[ni] = __builtin_amdgcn_mfma_f32_16x16x32_bf16(a, bb, accE[ni], 0, 0, 0);
        }
    }
#pragma unroll
    for (int ni = 0; ni < 16; ++ni)
#pragma unroll
        for (int r = 0; r < 4; ++r) {
            const int dp = w * 16 + q * 4 + r;
            const int cp = ni * 16 + r16;
            E_lds[dp * 264 + cp] = (unsigned short)f2bf(accE[ni][r]);
        }
    __syncthreads();

    // ---- Phase 2: S = E * Wv_h^T  (M=dp 64, N=d 64, K=c' 256). wave w: dp strip w*16.
    f32x4 accS[4];
#pragma unroll
    for (int ni = 0; ni < 4; ++ni) accS[ni] = (f32x4){0.f,0.f,0.f,0.f};

    for (int kk = 0; kk < 8; ++kk) {
        const int c0 = kk * 32 + q * 8;
        const bf16x8 a = *(const bf16x8*)(E_lds + (size_t)(w * 16 + r16) * 264 + c0);
        bf16x8 bb[4];
#pragma unroll
        for (int ni = 0; ni < 4; ++ni) {
            const f32x4* vp = (const f32x4*)(Wv + (size_t)(h * 64 + ni * 16 + r16) * CKV_ + c0);
            f32x4 v0 = vp[0], v1 = vp[1];
            bb[ni][0] = f2bf(v0.x); bb[ni][1] = f2bf(v0.y);
            bb[ni][2] = f2bf(v0.z); bb[ni][3] = f2bf(v0.w);
            bb[ni][4] = f2bf(v1.x); bb[ni][5] = f2bf(v1.y);
            bb[ni][6] = f2bf(v1.z); bb[ni][7] = f2bf(v1.w);
        }
#pragma unroll
        for (int ni = 0; ni < 4; ++ni)
            accS[ni] = __builtin_amdgcn_mfma_f32_16x16x32_bf16(a, bb[ni], accS[ni], 0, 0, 0);
    }
#pragma unroll
    for (int ni = 0; ni < 4; ++ni)
#pragma unroll
        for (int r = 0; r < 4; ++r) {
            const int dp = w * 16 + q * 4 + r;
            const int d  = ni * 16 + r16;
            S_lds[dp * 68 + d] = accS[ni][r];
        }
    __syncthreads();

    // ---- Phase 3: R = Wo_h * S^T  (M=c 256, N=dp 64, K=d 64). wave w: c strip w*64.
    f32x4 accR[4][4];
#pragma unroll
    for (int mi = 0; mi < 4; ++mi)
#pragma unroll
        for (int ni = 0; ni < 4; ++ni) accR[mi][ni] = (f32x4){0.f,0.f,0.f,0.f};

    for (int kk = 0; kk < 2; ++kk) {
        const int d0 = kk * 32 + q * 8;
        bf16x8 a[4];
#pragma unroll
        for (int mi = 0; mi < 4; ++mi) {
            const f32x4* op = (const f32x4*)(Wo + (size_t)(w * 64 + mi * 16 + r16) * HD_ + h * 64 + d0);
            f32x4 v0 = op[0], v1 = op[1];
            a[mi][0] = f2bf(v0.x); a[mi][1] = f2bf(v0.y);
            a[mi][2] = f2bf(v0.z); a[mi][3] = f2bf(v0.w);
            a[mi][4] = f2bf(v1.x); a[mi][5] = f2bf(v1.y);
            a[mi][6] = f2bf(v1.z); a[mi][7] = f2bf(v1.w);
        }
        bf16x8 bb[4];
#pragma unroll
        for (int ni = 0; ni < 4; ++ni) {
            // B[k=d][n=dp] = S[dp][d] -> row dp contiguous in d
            const float* sp = S_lds + (size_t)(ni * 16 + r16) * 68 + d0;
            const f32x4 v0 = *(const f32x4*)sp;
            const f32x4 v1 = *(const f32x4*)(sp + 4);
            bb[ni][0] = f2bf(v0.x); bb[ni][1] = f2bf(v0.y);
            bb[ni][2] = f2bf(v0.z); bb[ni][3] = f2bf(v0.w);
            bb[ni][4] = f2bf(v1.x); bb[ni][5] = f2bf(v1.y);
            bb[ni][6] = f2bf(v1.z); bb[ni][7] = f2bf(v1.w);
        }
#pragma unroll
        for (int mi = 0; mi < 4; ++mi)
#pragma unroll
            for (int ni = 0; ni < 4; ++ni)
                accR[mi][ni] = __builtin_amdgcn_mfma_f32_16x16x32_bf16(
                    a[mi], bb[ni], accR[mi][ni], 0, 0, 0);
    }
#pragma unroll
    for (int mi = 0; mi < 4; ++mi)
#pragma unroll
        for (int ni = 0; ni < 4; ++ni)
#pragma unroll
            for (int r = 0; r < 4; ++r) {
                const int c  = w * 64 + mi * 16 + q * 4 + r;
                const int dp = ni * 16 + r16;
                Rbuf[((size_t)b * CQ_ + c) * HD_ + h * 64 + dp] = accR[mi][ni][r];
            }
}

// -------------------------------------------------------------------------
// Kernel 4: N[b] = R[b] @ Wq   (256x512)@(512x256), fp32 tiled 32x32.
// -------------------------------------------------------------------------
__global__ __launch_bounds__(256) void fold_n_kernel(
    const float* __restrict__ Rbuf,
    const float* __restrict__ Wq,
    float* __restrict__ Nbuf)
{
    const int cqb = blockIdx.x * 32;
    const int cb  = blockIdx.y * 32;
    const int b   = blockIdx.z;
    const int tid = threadIdx.x;
    const int tx = tid & 15, ty = tid >> 4;

    __shared__ float Rt[32][33];
    __shared__ float Wt[32][33];

    float a00 = 0.f, a01 = 0.f, a10 = 0.f, a11 = 0.f;
    for (int ko = 0; ko < HD_; ko += 32) {
#pragma unroll
        for (int i = 0; i < 4; ++i) {
            const int lin = tid + i * 256;
            const int rr = lin >> 5, cc = lin & 31;
            Rt[rr][cc] = Rbuf[((size_t)b * CQ_ + cb + rr) * HD_ + ko + cc];
            Wt[rr][cc] = Wq[(size_t)(ko + rr) * CQ_ + cqb + cc];
        }
        __syncthreads();
#pragma unroll
        for (int k = 0; k < 32; ++k) {
            const float r0 = Rt[ty * 2][k],     r1 = Rt[ty * 2 + 1][k];
            const float w0 = Wt[k][tx * 2],     w1 = Wt[k][tx * 2 + 1];
            a00 += r0 * w0; a01 += r0 * w1; a10 += r1 * w0; a11 += r1 * w1;
        }
        __syncthreads();
    }
    float* np = Nbuf + ((size_t)b * CQ_ + cb + ty * 2) * CQ_ + cqb + tx * 2;
    np[0] = a00; np[1] = a01; np[CQ_] = a10; np[CQ_ + 1] = a11;
}

// -------------------------------------------------------------------------
// Kernel 5: out[b][c][n] = gamma * sum_cq N[b][c][cq]*x_q[b][cq][n] + x_q[b][c][n]
// MFMA mapping: M=c, N=n, K=cq.  Block tile 64(c) x 128(n), 4 waves 2x2.
// -------------------------------------------------------------------------
__global__ __launch_bounds__(256) void final_kernel(
    const float* __restrict__ Nbuf,
    const float* __restrict__ x_q,
    const float* __restrict__ gamma,
    float* __restrict__ out)
{
    const int nblk = blockIdx.x * 128;   // 0..15
    const int cblk = blockIdx.y * 64;    // 0..3
    const int b    = blockIdx.z;
    const int tid  = threadIdx.x;
    const int w    = tid >> 6;
    const int L    = tid & 63;
    const int row16 = L & 15;
    const int quad  = L >> 4;
    const int wc = (w >> 1) * 32;
    const int wn = (w & 1) * 64;

    const float* Nb = Nbuf + (size_t)b * CQ_ * CQ_;
    const float* Xb = x_q + (size_t)b * CQ_ * NQ_;
    const float g = gamma[0];

    f32x4 acc[2][4];
#pragma unroll
    for (int mi = 0; mi < 2; ++mi)
#pragma unroll
        for (int ni = 0; ni < 4; ++ni) acc[mi][ni] = (f32x4){0.f,0.f,0.f,0.f};

    for (int kk = 0; kk < 8; ++kk) {
        const int c0 = kk * 32 + quad * 8;

        bf16x8 afrag[2];
#pragma unroll
        for (int mi = 0; mi < 2; ++mi) {
            const int c = cblk + wc + mi * 16 + row16;
            const f32x4* np = (const f32x4*)(Nb + (size_t)c * CQ_ + c0);
            f32x4 n0 = np[0], n1 = np[1];
            afrag[mi][0] = f2bf(n0.x); afrag[mi][1] = f2bf(n0.y);
            afrag[mi][2] = f2bf(n0.z); afrag[mi][3] = f2bf(n0.w);
            afrag[mi][4] = f2bf(n1.x); afrag[mi][5] = f2bf(n1.y);
            afrag[mi][6] = f2bf(n1.z); afrag[mi][7] = f2bf(n1.w);
        }

        bf16x8 bfrag[4];
#pragma unroll
        for (int ni = 0; ni < 4; ++ni) {
            const int n = nblk + wn + ni * 16 + row16;
            const float* xp = Xb + (size_t)c0 * NQ_ + n;
#pragma unroll
            for (int j = 0; j < 8; ++j) bfrag[ni][j] = f2bf(xp[(size_t)j * NQ_]);
        }

#pragma unroll
        for (int mi = 0; mi < 2; ++mi)
#pragma unroll
            for (int ni = 0; ni < 4; ++ni)
                acc[mi][ni] = __builtin_amdgcn_mfma_f32_16x16x32_bf16(
                    afrag[mi], bfrag[ni], acc[mi][ni], 0, 0, 0);
    }

#pragma unroll
    for (int mi = 0; mi < 2; ++mi) {
#pragma unroll
        for (int ni = 0; ni < 4; ++ni) {
#pragma unroll
            for (int r = 0; r < 4; ++r) {
                const int c = cblk + wc + mi * 16 + quad * 4 + r;
                const int n = nblk + wn + ni * 16 + row16;
                const size_t idx = ((size_t)b * CQ_ + c) * NQ_ + n;
                out[idx] = g * acc[mi][ni][r] + Xb[(size_t)c * NQ_ + n];
            }
        }
    }
}

// -------------------------------------------------------------------------
extern "C" void kernel_launch(void* const* d_in, const int* in_sizes, int n_in,
                              void* d_out, int out_size, void* d_ws, size_t ws_size,
                              hipStream_t stream) {
    const float* x_q   = (const float*)d_in[0];
    const float* x_kv  = (const float*)d_in[1];
    const float* Wq    = (const float*)d_in[2];
    const float* Wk    = (const float*)d_in[3];
    const float* Wv    = (const float*)d_in[4];
    const float* Wo    = (const float*)d_in[5];
    const float* gamma = (const float*)d_in[6];
    float* out = (float*)d_out;

    char* ws = (char*)d_ws;
    // ws layout (bytes):
    //   Gpart f32  [8][4][256][256]  0        .. 8388608
    //   Gsum  bf16 [4][256][256]     8388608  .. 8912896
    //   Rbuf  f32  [4][256][512]     8912896  .. 11010048
    //   Nbuf  f32  [4][256][256]     11010048 .. 12058624
    float* Gpart = (float*)(ws);
    unsigned short* Gsum = (unsigned short*)(ws + 8388608);
    float* Rbuf  = (float*)(ws + 8912896);
    float* Nbuf  = (float*)(ws + 11010048);

    gram_kernel<<<dim3(8, 8, 4), 256, 0, stream>>>(x_kv, Gpart);
    reduce_g_kernel<<<dim3(256), 256, 0, stream>>>(Gpart, Gsum);
    fold_esr_kernel<<<dim3(8, 4), 256, 0, stream>>>(Gsum, Wk, Wv, Wo, Rbuf);
    fold_n_kernel<<<dim3(8, 8, 4), 256, 0, stream>>>(Rbuf, Wq, Nbuf);
    final_kernel<<<dim3(16, 4, 4), 256, 0, stream>>>(Nbuf, x_q, gamma, out);
}

// Round 3
// 128.769 us; speedup vs baseline: 1.3432x; 1.2167x over previous
//
#include <hip/hip_runtime.h>
#include <hip/hip_bf16.h>
#include <stdint.h>

// Problem constants
#define B_    4
#define CQ_   256
#define CKV_  256
#define NQ_   2048
#define NKV_  2048
#define H_    8
#define DK_   64
#define HD_   512   // H_*DK_

typedef __attribute__((ext_vector_type(8))) short bf16x8;
typedef __attribute__((ext_vector_type(4))) float f32x4;

__device__ __forceinline__ short f2bf(float f) {
    unsigned u = __builtin_bit_cast(unsigned, f);
    u = (u + 0x7FFFu + ((u >> 16) & 1u)) >> 16;   // RNE truncate to bf16
    return (short)u;
}

// -------------------------------------------------------------------------
// Kernel 1: prep.  blocks [0,1024): x_kv f32 -> xkv_bf bf16 (same layout).
//                  blocks [1024,1536): x_q [b][cq][n] -> xqt_bf [b][n][cq].
// -------------------------------------------------------------------------
__global__ __launch_bounds__(256) void prep_kernel(
    const float* __restrict__ x_kv,
    const float* __restrict__ x_q,
    unsigned short* __restrict__ xkv_bf,
    unsigned short* __restrict__ xqt_bf)
{
    const int tid = threadIdx.x;
    int bid = blockIdx.x;
    if (bid < 1024) {
        const size_t base = ((size_t)bid * 256 + tid) * 8;
        const f32x4 v0 = *(const f32x4*)(x_kv + base);
        const f32x4 v1 = *(const f32x4*)(x_kv + base + 4);
        bf16x8 o;
        o[0] = f2bf(v0.x); o[1] = f2bf(v0.y); o[2] = f2bf(v0.z); o[3] = f2bf(v0.w);
        o[4] = f2bf(v1.x); o[5] = f2bf(v1.y); o[6] = f2bf(v1.z); o[7] = f2bf(v1.w);
        *(bf16x8*)(xkv_bf + base) = o;
    } else {
        bid -= 1024;                      // 512 transpose blocks
        const int b   = bid >> 7;         // 0..3
        const int t   = bid & 127;        // 0..127
        const int cq0 = (t & 3) * 64;     // 4 cq tiles
        const int n0  = (t >> 2) * 64;    // 32 n tiles

        __shared__ float tile[64][65];
        const float* src = x_q + (size_t)b * CQ_ * NQ_;
        const int r_l = tid >> 4;          // 0..15
        const int c_l = (tid & 15) * 4;    // 0..60
#pragma unroll
        for (int i = 0; i < 4; ++i) {
            const int row = r_l + 16 * i;
            const f32x4 v = *(const f32x4*)(src + (size_t)(cq0 + row) * NQ_ + n0 + c_l);
            tile[row][c_l] = v.x; tile[row][c_l + 1] = v.y;
            tile[row][c_l + 2] = v.z; tile[row][c_l + 3] = v.w;
        }
        __syncthreads();
        unsigned short* dst = xqt_bf + (size_t)b * NQ_ * CQ_;
        const int cq_l = (tid & 7) * 8;
#pragma unroll
        for (int j = 0; j < 2; ++j) {
            const int n_l = (tid >> 3) + 32 * j;
            bf16x8 o;
#pragma unroll
            for (int k = 0; k < 8; ++k) o[k] = f2bf(tile[cq_l + k][n_l]);
            *(bf16x8*)(dst + (size_t)(n0 + n_l) * CQ_ + cq0 + cq_l) = o;
        }
    }
}

// -------------------------------------------------------------------------
// Kernel 2: pq.  Batch-independent folds, K=64 each:
//  bid<64:  P[c][h*256+c'] = sum_d Wo[c][h64+d]*Wv[h64+d][c']
//  bid>=64: Qt[h*256+cq][c''] = sum_d Wk[h64+d][c'']*Wq[h64+d][cq]
// Block tile 64(m) x 128(n), 4 waves 2x2.  Outputs bf16.
// -------------------------------------------------------------------------
__global__ __launch_bounds__(256) void pq_kernel(
    const float* __restrict__ Wq,
    const float* __restrict__ Wk,
    const float* __restrict__ Wv,
    const float* __restrict__ Wo,
    unsigned short* __restrict__ P,
    unsigned short* __restrict__ Qt)
{
    const int bid = blockIdx.x;
    const bool isP = (bid < 64);
    const int lb = isP ? bid : bid - 64;
    const int h = lb >> 3;
    const int t = lb & 7;
    const int tm = (t >> 1) * 64;
    const int tn = (t & 1) * 128;
    const int tid = threadIdx.x;
    const int w = tid >> 6, L = tid & 63;
    const int r16 = L & 15, q = L >> 4;
    const int wm = (w >> 1) * 32, wn = (w & 1) * 64;

    f32x4 acc[2][4];
#pragma unroll
    for (int mi = 0; mi < 2; ++mi)
#pragma unroll
        for (int ni = 0; ni < 4; ++ni) acc[mi][ni] = (f32x4){0.f,0.f,0.f,0.f};

    for (int kk = 0; kk < 2; ++kk) {
        const int d0 = kk * 32 + q * 8;   // k within head dim
        bf16x8 a[2], bb[4];
        if (isP) {
            // A[m=c][k=d] = Wo[c][h64+d]  (contiguous)
#pragma unroll
            for (int mi = 0; mi < 2; ++mi) {
                const int m = tm + wm + mi * 16 + r16;
                const f32x4* p = (const f32x4*)(Wo + (size_t)m * HD_ + h * 64 + d0);
                f32x4 v0 = p[0], v1 = p[1];
                a[mi][0]=f2bf(v0.x); a[mi][1]=f2bf(v0.y); a[mi][2]=f2bf(v0.z); a[mi][3]=f2bf(v0.w);
                a[mi][4]=f2bf(v1.x); a[mi][5]=f2bf(v1.y); a[mi][6]=f2bf(v1.z); a[mi][7]=f2bf(v1.w);
            }
            // B[n=c'][k=d] = Wv[h64+d][c']  (strided)
#pragma unroll
            for (int ni = 0; ni < 4; ++ni) {
                const int n = tn + wn + ni * 16 + r16;
#pragma unroll
                for (int j = 0; j < 8; ++j)
                    bb[ni][j] = f2bf(Wv[(size_t)(h * 64 + d0 + j) * CKV_ + n]);
            }
        } else {
            // A[m=cq][k=d] = Wq[h64+d][cq]  (strided)
#pragma unroll
            for (int mi = 0; mi < 2; ++mi) {
                const int m = tm + wm + mi * 16 + r16;
#pragma unroll
                for (int j = 0; j < 8; ++j)
                    a[mi][j] = f2bf(Wq[(size_t)(h * 64 + d0 + j) * CQ_ + m]);
            }
            // B[n=c''][k=d] = Wk[h64+d][c'']  (strided)
#pragma unroll
            for (int ni = 0; ni < 4; ++ni) {
                const int n = tn + wn + ni * 16 + r16;
#pragma unroll
                for (int j = 0; j < 8; ++j)
                    bb[ni][j] = f2bf(Wk[(size_t)(h * 64 + d0 + j) * CKV_ + n]);
            }
        }
#pragma unroll
        for (int mi = 0; mi < 2; ++mi)
#pragma unroll
            for (int ni = 0; ni < 4; ++ni)
                acc[mi][ni] = __builtin_amdgcn_mfma_f32_16x16x32_bf16(
                    a[mi], bb[ni], acc[mi][ni], 0, 0, 0);
    }

#pragma unroll
    for (int mi = 0; mi < 2; ++mi)
#pragma unroll
        for (int ni = 0; ni < 4; ++ni)
#pragma unroll
            for (int r = 0; r < 4; ++r) {
                const int m = tm + wm + mi * 16 + q * 4 + r;
                const int n = tn + wn + ni * 16 + r16;
                if (isP)  P [(size_t)m * 2048 + h * 256 + n] = (unsigned short)f2bf(acc[mi][ni][r]);
                else      Qt[((size_t)h * 256 + m) * 256 + n] = (unsigned short)f2bf(acc[mi][ni][r]);
            }
}

// -------------------------------------------------------------------------
// Kernel 3: Gram partials from bf16 x_kv.  Pure bf16x8 loads + MFMA.
// Gpart[kc][b][c][c'] = sum_{n in chunk} x[c][n]*x[c'][n]
// -------------------------------------------------------------------------
__global__ __launch_bounds__(256) void gram_kernel(
    const unsigned short* __restrict__ xkv_bf,
    float* __restrict__ Gpart)
{
    const int kc = blockIdx.x;            // 0..7
    const int t  = blockIdx.y;            // 0..7
    const int b  = blockIdx.z;
    const int tid = threadIdx.x;
    const int w = tid >> 6, L = tid & 63;
    const int r16 = L & 15, q = L >> 4;
    const int tc  = (t >> 1) * 64;
    const int tcp = (t & 1) * 128;
    const int wm = (w >> 1) * 32, wn = (w & 1) * 64;
    const int n0 = kc * 256;

    const unsigned short* Xb = xkv_bf + (size_t)b * CKV_ * NKV_;

    f32x4 acc[2][4];
#pragma unroll
    for (int mi = 0; mi < 2; ++mi)
#pragma unroll
        for (int ni = 0; ni < 4; ++ni) acc[mi][ni] = (f32x4){0.f,0.f,0.f,0.f};

    for (int kk = 0; kk < 8; ++kk) {
        const int nbase = n0 + kk * 32 + q * 8;
        bf16x8 a[2], bb[4];
#pragma unroll
        for (int mi = 0; mi < 2; ++mi)
            a[mi] = *(const bf16x8*)(Xb + (size_t)(tc + wm + mi * 16 + r16) * NKV_ + nbase);
#pragma unroll
        for (int ni = 0; ni < 4; ++ni)
            bb[ni] = *(const bf16x8*)(Xb + (size_t)(tcp + wn + ni * 16 + r16) * NKV_ + nbase);
#pragma unroll
        for (int mi = 0; mi < 2; ++mi)
#pragma unroll
            for (int ni = 0; ni < 4; ++ni)
                acc[mi][ni] = __builtin_amdgcn_mfma_f32_16x16x32_bf16(
                    a[mi], bb[ni], acc[mi][ni], 0, 0, 0);
    }

    float* Gp = Gpart + ((size_t)kc * B_ + b) * 65536;
#pragma unroll
    for (int mi = 0; mi < 2; ++mi)
#pragma unroll
        for (int ni = 0; ni < 4; ++ni)
#pragma unroll
            for (int r = 0; r < 4; ++r)
                Gp[(tc + wm + mi * 16 + q * 4 + r) * 256 + tcp + wn + ni * 16 + r16]
                    = acc[mi][ni][r];
}

// -------------------------------------------------------------------------
// Kernel 4: reduce split-K partials, scale 1/64, to bf16.
// -------------------------------------------------------------------------
__global__ __launch_bounds__(256) void reduce_g_kernel(
    const float* __restrict__ Gpart,
    unsigned short* __restrict__ Gsum)
{
    const int idx4 = blockIdx.x * 256 + threadIdx.x;
    const size_t base = (size_t)idx4 * 4;
    f32x4 s = (f32x4){0.f,0.f,0.f,0.f};
#pragma unroll
    for (int kc = 0; kc < 8; ++kc) {
        f32x4 v = *(const f32x4*)(Gpart + (size_t)kc * 262144 + base);
        s.x += v.x; s.y += v.y; s.z += v.z; s.w += v.w;
    }
    const float sc = 1.0f / 64.0f;
    ushort4 o;
    o.x = (unsigned short)f2bf(s.x * sc);
    o.y = (unsigned short)f2bf(s.y * sc);
    o.z = (unsigned short)f2bf(s.z * sc);
    o.w = (unsigned short)f2bf(s.w * sc);
    *(ushort4*)(Gsum + base) = o;
}

// -------------------------------------------------------------------------
// Kernel 5: zgemm.  Per (b,h): Zt_b[cq][h*256+c'] = sum_{c''} Qt[(h,cq)][c'']*Gs_b[c'][c'']
// (uses G symmetry: B[n=c'][k=c''] = Gs row c', contiguous).  Output bf16.
// Block tile 64(cq) x 128(c'), grid (8,8,4) = 256 blocks.
// -------------------------------------------------------------------------
__global__ __launch_bounds__(256) void zgemm_kernel(
    const unsigned short* __restrict__ Qt,
    const unsigned short* __restrict__ Gsum,
    unsigned short* __restrict__ Zt)
{
    const int t = blockIdx.x;
    const int h = blockIdx.y;
    const int b = blockIdx.z;
    const int tid = threadIdx.x;
    const int w = tid >> 6, L = tid & 63;
    const int r16 = L & 15, q = L >> 4;
    const int tm = (t >> 1) * 64;
    const int tn = (t & 1) * 128;
    const int wm = (w >> 1) * 32, wn = (w & 1) * 64;

    const unsigned short* Qh = Qt + (size_t)h * 256 * 256;
    const unsigned short* Gb = Gsum + (size_t)b * 65536;

    f32x4 acc[2][4];
#pragma unroll
    for (int mi = 0; mi < 2; ++mi)
#pragma unroll
        for (int ni = 0; ni < 4; ++ni) acc[mi][ni] = (f32x4){0.f,0.f,0.f,0.f};

    for (int kk = 0; kk < 8; ++kk) {
        const int c0 = kk * 32 + q * 8;
        bf16x8 a[2], bb[4];
#pragma unroll
        for (int mi = 0; mi < 2; ++mi)
            a[mi] = *(const bf16x8*)(Qh + (size_t)(tm + wm + mi * 16 + r16) * 256 + c0);
#pragma unroll
        for (int ni = 0; ni < 4; ++ni)
            bb[ni] = *(const bf16x8*)(Gb + (size_t)(tn + wn + ni * 16 + r16) * 256 + c0);
#pragma unroll
        for (int mi = 0; mi < 2; ++mi)
#pragma unroll
            for (int ni = 0; ni < 4; ++ni)
                acc[mi][ni] = __builtin_amdgcn_mfma_f32_16x16x32_bf16(
                    a[mi], bb[ni], acc[mi][ni], 0, 0, 0);
    }

    unsigned short* Zb = Zt + (size_t)b * 256 * 2048;
#pragma unroll
    for (int mi = 0; mi < 2; ++mi)
#pragma unroll
        for (int ni = 0; ni < 4; ++ni)
#pragma unroll
            for (int r = 0; r < 4; ++r) {
                const int m = tm + wm + mi * 16 + q * 4 + r;       // cq
                const int n = tn + wn + ni * 16 + r16;             // c'
                Zb[(size_t)m * 2048 + h * 256 + n] = (unsigned short)f2bf(acc[mi][ni][r]);
            }
}

// -------------------------------------------------------------------------
// Kernel 6: ngemm split-K.  Npart[s][b][c][cq] = sum_{k in chunk} P[c][k]*Zt_b[cq][k]
// K=2048 split 4x512.  Grid (8 tiles, 4 splitk, 4 b) = 128 blocks.
// -------------------------------------------------------------------------
__global__ __launch_bounds__(256) void ngemm_kernel(
    const unsigned short* __restrict__ P,
    const unsigned short* __restrict__ Zt,
    float* __restrict__ Npart)
{
    const int t = blockIdx.x;
    const int sk = blockIdx.y;
    const int b = blockIdx.z;
    const int tid = threadIdx.x;
    const int w = tid >> 6, L = tid & 63;
    const int r16 = L & 15, q = L >> 4;
    const int tm = (t >> 1) * 64;
    const int tn = (t & 1) * 128;
    const int wm = (w >> 1) * 32, wn = (w & 1) * 64;
    const int k0base = sk * 512;

    const unsigned short* Zb = Zt + (size_t)b * 256 * 2048;

    f32x4 acc[2][4];
#pragma unroll
    for (int mi = 0; mi < 2; ++mi)
#pragma unroll
        for (int ni = 0; ni < 4; ++ni) acc[mi][ni] = (f32x4){0.f,0.f,0.f,0.f};

    for (int kk = 0; kk < 16; ++kk) {
        const int k0 = k0base + kk * 32 + q * 8;
        bf16x8 a[2], bb[4];
#pragma unroll
        for (int mi = 0; mi < 2; ++mi)
            a[mi] = *(const bf16x8*)(P + (size_t)(tm + wm + mi * 16 + r16) * 2048 + k0);
#pragma unroll
        for (int ni = 0; ni < 4; ++ni)
            bb[ni] = *(const bf16x8*)(Zb + (size_t)(tn + wn + ni * 16 + r16) * 2048 + k0);
#pragma unroll
        for (int mi = 0; mi < 2; ++mi)
#pragma unroll
            for (int ni = 0; ni < 4; ++ni)
                acc[mi][ni] = __builtin_amdgcn_mfma_f32_16x16x32_bf16(
                    a[mi], bb[ni], acc[mi][ni], 0, 0, 0);
    }

    float* Np = Npart + ((size_t)sk * B_ + b) * 65536;
#pragma unroll
    for (int mi = 0; mi < 2; ++mi)
#pragma unroll
        for (int ni = 0; ni < 4; ++ni)
#pragma unroll
            for (int r = 0; r < 4; ++r)
                Np[(tm + wm + mi * 16 + q * 4 + r) * 256 + tn + wn + ni * 16 + r16]
                    = acc[mi][ni][r];
}

// -------------------------------------------------------------------------
// Kernel 7: reduce N partials -> bf16.
// -------------------------------------------------------------------------
__global__ __launch_bounds__(256) void reduce_n_kernel(
    const float* __restrict__ Npart,
    unsigned short* __restrict__ Nbf)
{
    const int idx4 = blockIdx.x * 256 + threadIdx.x;  // 65536 total
    const size_t base = (size_t)idx4 * 4;
    f32x4 s = (f32x4){0.f,0.f,0.f,0.f};
#pragma unroll
    for (int sk = 0; sk < 4; ++sk) {
        f32x4 v = *(const f32x4*)(Npart + (size_t)sk * 262144 + base);
        s.x += v.x; s.y += v.y; s.z += v.z; s.w += v.w;
    }
    ushort4 o;
    o.x = (unsigned short)f2bf(s.x);
    o.y = (unsigned short)f2bf(s.y);
    o.z = (unsigned short)f2bf(s.z);
    o.w = (unsigned short)f2bf(s.w);
    *(ushort4*)(Nbf + base) = o;
}

// -------------------------------------------------------------------------
// Kernel 8: final.  out[b][c][n] = g * sum_cq Nbf[b][c][cq]*xqt[b][n][cq] + x_q[b][c][n]
// Pure bf16x8 loads + MFMA.  Block tile 64(c) x 128(n), grid (16,4,4).
// -------------------------------------------------------------------------
__global__ __launch_bounds__(256) void final_kernel(
    const unsigned short* __restrict__ Nbf,
    const unsigned short* __restrict__ xqt_bf,
    const float* __restrict__ x_q,
    const float* __restrict__ gamma,
    float* __restrict__ out)
{
    const int nblk = blockIdx.x * 128;
    const int cblk = blockIdx.y * 64;
    const int b    = blockIdx.z;
    const int tid  = threadIdx.x;
    const int w = tid >> 6, L = tid & 63;
    const int r16 = L & 15, q = L >> 4;
    const int wc = (w >> 1) * 32;
    const int wn = (w & 1) * 64;

    const unsigned short* Nb = Nbf + (size_t)b * 65536;
    const unsigned short* Xq = xqt_bf + (size_t)b * NQ_ * CQ_;
    const float* Xb = x_q + (size_t)b * CQ_ * NQ_;
    const float g = gamma[0];

    f32x4 acc[2][4];
#pragma unroll
    for (int mi = 0; mi < 2; ++mi)
#pragma unroll
        for (int ni = 0; ni < 4; ++ni) acc[mi][ni] = (f32x4){0.f,0.f,0.f,0.f};

    for (int kk = 0; kk < 8; ++kk) {
        const int c0 = kk * 32 + q * 8;
        bf16x8 a[2], bb[4];
#pragma unroll
        for (int mi = 0; mi < 2; ++mi)
            a[mi] = *(const bf16x8*)(Nb + (size_t)(cblk + wc + mi * 16 + r16) * 256 + c0);
#pragma unroll
        for (int ni = 0; ni < 4; ++ni)
            bb[ni] = *(const bf16x8*)(Xq + (size_t)(nblk + wn + ni * 16 + r16) * 256 + c0);
#pragma unroll
        for (int mi = 0; mi < 2; ++mi)
#pragma unroll
            for (int ni = 0; ni < 4; ++ni)
                acc[mi][ni] = __builtin_amdgcn_mfma_f32_16x16x32_bf16(
                    a[mi], bb[ni], acc[mi][ni], 0, 0, 0);
    }

#pragma unroll
    for (int mi = 0; mi < 2; ++mi)
#pragma unroll
        for (int ni = 0; ni < 4; ++ni)
#pragma unroll
            for (int r = 0; r < 4; ++r) {
                const int c = cblk + wc + mi * 16 + q * 4 + r;
                const int n = nblk + wn + ni * 16 + r16;
                const size_t idx = ((size_t)b * CQ_ + c) * NQ_ + n;
                out[idx] = g * acc[mi][ni][r] + Xb[(size_t)c * NQ_ + n];
            }
}

// -------------------------------------------------------------------------
extern "C" void kernel_launch(void* const* d_in, const int* in_sizes, int n_in,
                              void* d_out, int out_size, void* d_ws, size_t ws_size,
                              hipStream_t stream) {
    const float* x_q   = (const float*)d_in[0];
    const float* x_kv  = (const float*)d_in[1];
    const float* Wq    = (const float*)d_in[2];
    const float* Wk    = (const float*)d_in[3];
    const float* Wv    = (const float*)d_in[4];
    const float* Wo    = (const float*)d_in[5];
    const float* gamma = (const float*)d_in[6];
    float* out = (float*)d_out;

    char* ws = (char*)d_ws;
    // ws layout (bytes), total 24,117,248:
    //   xkv_bf bf16 [4][256][2048]        0 ..  4194304
    //   xqt_bf bf16 [4][2048][256]  4194304 ..  8388608
    //   Gpart  f32  [8][4][256][256]8388608 .. 16777216   (aliased by Npart)
    //   Npart  f32  [4][4][256][256]8388608 .. 12582912   (after reduce_g done)
    //   Gsum   bf16 [4][256][256]  16777216 .. 17301504
    //   P      bf16 [256][2048]    17301504 .. 18350080
    //   Qt     bf16 [2048][256]    18350080 .. 19398656
    //   Zt     bf16 [4][256][2048] 19398656 .. 23592960
    //   Nbf    bf16 [4][256][256]  23592960 .. 24117248
    unsigned short* xkv_bf = (unsigned short*)(ws);
    unsigned short* xqt_bf = (unsigned short*)(ws + 4194304);
    float*          Gpart  = (float*)(ws + 8388608);
    float*          Npart  = (float*)(ws + 8388608);
    unsigned short* Gsum   = (unsigned short*)(ws + 16777216);
    unsigned short* P      = (unsigned short*)(ws + 17301504);
    unsigned short* Qt     = (unsigned short*)(ws + 18350080);
    unsigned short* Zt     = (unsigned short*)(ws + 19398656);
    unsigned short* Nbf    = (unsigned short*)(ws + 23592960);

    prep_kernel<<<dim3(1536), 256, 0, stream>>>(x_kv, x_q, xkv_bf, xqt_bf);
    pq_kernel<<<dim3(128), 256, 0, stream>>>(Wq, Wk, Wv, Wo, P, Qt);
    gram_kernel<<<dim3(8, 8, 4), 256, 0, stream>>>(xkv_bf, Gpart);
    reduce_g_kernel<<<dim3(256), 256, 0, stream>>>(Gpart, Gsum);
    zgemm_kernel<<<dim3(8, 8, 4), 256, 0, stream>>>(Qt, Gsum, Zt);
    ngemm_kernel<<<dim3(8, 4, 4), 256, 0, stream>>>(P, Zt, Npart);
    reduce_n_kernel<<<dim3(256), 256, 0, stream>>>(Npart, Nbf);
    final_kernel<<<dim3(16, 4, 4), 256, 0, stream>>>(Nbf, xqt_bf, x_q, gamma, out);
}

// Round 4
// 125.911 us; speedup vs baseline: 1.3737x; 1.0227x over previous
//
#include <hip/hip_runtime.h>
#include <hip/hip_bf16.h>
#include <stdint.h>

// Problem constants
#define B_    4
#define CQ_   256
#define CKV_  256
#define NQ_   2048
#define NKV_  2048
#define H_    8
#define DK_   64
#define HD_   512   // H_*DK_

typedef __attribute__((ext_vector_type(8))) short bf16x8;
typedef __attribute__((ext_vector_type(4))) float f32x4;

__device__ __forceinline__ short f2bf(float f) {
    unsigned u = __builtin_bit_cast(unsigned, f);
    u = (u + 0x7FFFu + ((u >> 16) & 1u)) >> 16;   // RNE truncate to bf16
    return (short)u;
}

#define MFMA16(a, b, c) __builtin_amdgcn_mfma_f32_16x16x32_bf16((a), (b), (c), 0, 0, 0)

// -------------------------------------------------------------------------
// Kernel 1: prep + pq fused (independent work, block-range dispatch).
//  [0,1024):    x_kv f32 -> xkv_bf bf16 (same layout)
//  [1024,1536): x_q [b][cq][n] -> xqt_bf [b][n][cq] (transpose, bf16)
//  [1536,1664): pq folds:
//     bid-1536 <64:  P[c][h*256+c'] = sum_d Wo[c][h64+d]*Wv[h64+d][c']
//     else:          Qt[h*256+cq][c''] = sum_d Wk[h64+d][c'']*Wq[h64+d][cq]
// -------------------------------------------------------------------------
__global__ __launch_bounds__(256) void prep_pq_kernel(
    const float* __restrict__ x_kv,
    const float* __restrict__ x_q,
    const float* __restrict__ Wq,
    const float* __restrict__ Wk,
    const float* __restrict__ Wv,
    const float* __restrict__ Wo,
    unsigned short* __restrict__ xkv_bf,
    unsigned short* __restrict__ xqt_bf,
    unsigned short* __restrict__ P,
    unsigned short* __restrict__ Qt)
{
    const int tid = threadIdx.x;
    int bid = blockIdx.x;
    if (bid < 1024) {
        const size_t base = ((size_t)bid * 256 + tid) * 8;
        const f32x4 v0 = *(const f32x4*)(x_kv + base);
        const f32x4 v1 = *(const f32x4*)(x_kv + base + 4);
        bf16x8 o;
        o[0] = f2bf(v0.x); o[1] = f2bf(v0.y); o[2] = f2bf(v0.z); o[3] = f2bf(v0.w);
        o[4] = f2bf(v1.x); o[5] = f2bf(v1.y); o[6] = f2bf(v1.z); o[7] = f2bf(v1.w);
        *(bf16x8*)(xkv_bf + base) = o;
        return;
    }
    if (bid < 1536) {
        bid -= 1024;                      // 512 transpose blocks
        const int b   = bid >> 7;
        const int t   = bid & 127;
        const int cq0 = (t & 3) * 64;
        const int n0  = (t >> 2) * 64;

        __shared__ float tile[64][65];
        const float* src = x_q + (size_t)b * CQ_ * NQ_;
        const int r_l = tid >> 4;
        const int c_l = (tid & 15) * 4;
#pragma unroll
        for (int i = 0; i < 4; ++i) {
            const int row = r_l + 16 * i;
            const f32x4 v = *(const f32x4*)(src + (size_t)(cq0 + row) * NQ_ + n0 + c_l);
            tile[row][c_l] = v.x; tile[row][c_l + 1] = v.y;
            tile[row][c_l + 2] = v.z; tile[row][c_l + 3] = v.w;
        }
        __syncthreads();
        unsigned short* dst = xqt_bf + (size_t)b * NQ_ * CQ_;
        const int cq_l = (tid & 7) * 8;
#pragma unroll
        for (int j = 0; j < 2; ++j) {
            const int n_l = (tid >> 3) + 32 * j;
            bf16x8 o;
#pragma unroll
            for (int k = 0; k < 8; ++k) o[k] = f2bf(tile[cq_l + k][n_l]);
            *(bf16x8*)(dst + (size_t)(n0 + n_l) * CQ_ + cq0 + cq_l) = o;
        }
        return;
    }

    // ---- pq part ----
    const int lb0 = bid - 1536;
    const bool isP = (lb0 < 64);
    const int lb = isP ? lb0 : lb0 - 64;
    const int h = lb >> 3;
    const int t = lb & 7;
    const int tm = (t >> 1) * 64;
    const int tn = (t & 1) * 128;
    const int w = tid >> 6, L = tid & 63;
    const int r16 = L & 15, q = L >> 4;
    const int wm = (w >> 1) * 32, wn = (w & 1) * 64;

    f32x4 acc[2][4];
#pragma unroll
    for (int mi = 0; mi < 2; ++mi)
#pragma unroll
        for (int ni = 0; ni < 4; ++ni) acc[mi][ni] = (f32x4){0.f,0.f,0.f,0.f};

#pragma unroll
    for (int kk = 0; kk < 2; ++kk) {
        const int d0 = kk * 32 + q * 8;
        bf16x8 a[2], bb[4];
        if (isP) {
#pragma unroll
            for (int mi = 0; mi < 2; ++mi) {
                const int m = tm + wm + mi * 16 + r16;
                const f32x4* p = (const f32x4*)(Wo + (size_t)m * HD_ + h * 64 + d0);
                f32x4 v0 = p[0], v1 = p[1];
                a[mi][0]=f2bf(v0.x); a[mi][1]=f2bf(v0.y); a[mi][2]=f2bf(v0.z); a[mi][3]=f2bf(v0.w);
                a[mi][4]=f2bf(v1.x); a[mi][5]=f2bf(v1.y); a[mi][6]=f2bf(v1.z); a[mi][7]=f2bf(v1.w);
            }
#pragma unroll
            for (int ni = 0; ni < 4; ++ni) {
                const int n = tn + wn + ni * 16 + r16;
#pragma unroll
                for (int j = 0; j < 8; ++j)
                    bb[ni][j] = f2bf(Wv[(size_t)(h * 64 + d0 + j) * CKV_ + n]);
            }
        } else {
#pragma unroll
            for (int mi = 0; mi < 2; ++mi) {
                const int m = tm + wm + mi * 16 + r16;
#pragma unroll
                for (int j = 0; j < 8; ++j)
                    a[mi][j] = f2bf(Wq[(size_t)(h * 64 + d0 + j) * CQ_ + m]);
            }
#pragma unroll
            for (int ni = 0; ni < 4; ++ni) {
                const int n = tn + wn + ni * 16 + r16;
#pragma unroll
                for (int j = 0; j < 8; ++j)
                    bb[ni][j] = f2bf(Wk[(size_t)(h * 64 + d0 + j) * CKV_ + n]);
            }
        }
#pragma unroll
        for (int mi = 0; mi < 2; ++mi)
#pragma unroll
            for (int ni = 0; ni < 4; ++ni)
                acc[mi][ni] = MFMA16(a[mi], bb[ni], acc[mi][ni]);
    }

#pragma unroll
    for (int mi = 0; mi < 2; ++mi)
#pragma unroll
        for (int ni = 0; ni < 4; ++ni)
#pragma unroll
            for (int r = 0; r < 4; ++r) {
                const int m = tm + wm + mi * 16 + q * 4 + r;
                const int n = tn + wn + ni * 16 + r16;
                if (isP)  P [(size_t)m * 2048 + h * 256 + n] = (unsigned short)f2bf(acc[mi][ni][r]);
                else      Qt[((size_t)h * 256 + m) * 256 + n] = (unsigned short)f2bf(acc[mi][ni][r]);
            }
}

// -------------------------------------------------------------------------
// Kernel 2: Gram partials.  64x64 tiles, split-K=8, grid (8,16,4)=512 blocks.
// Gpart[kc][b][c][c'] = sum_{n in chunk} x[c][n]*x[c'][n].
// Double-buffered K-loop: loads for step k+1 issue before MFMAs of step k.
// -------------------------------------------------------------------------
__global__ __launch_bounds__(256) void gram_kernel(
    const unsigned short* __restrict__ xkv_bf,
    float* __restrict__ Gpart)
{
    const int kc = blockIdx.x;            // 0..7
    const int t  = blockIdx.y;            // 0..15
    const int b  = blockIdx.z;
    const int tid = threadIdx.x;
    const int w = tid >> 6, L = tid & 63;
    const int r16 = L & 15, q = L >> 4;
    const int tm = (t >> 2) * 64;
    const int tn = (t & 3) * 64;
    const int wm = (w >> 1) * 32, wn = (w & 1) * 32;

    const unsigned short* Xb = xkv_bf + (size_t)b * CKV_ * NKV_;
    const unsigned short* A0 = Xb + (size_t)(tm + wm + r16) * NKV_;
    const unsigned short* A1 = A0 + (size_t)16 * NKV_;
    const unsigned short* B0 = Xb + (size_t)(tn + wn + r16) * NKV_;
    const unsigned short* B1 = B0 + (size_t)16 * NKV_;
    const int k0 = kc * 256 + q * 8;

    f32x4 acc[2][2];
#pragma unroll
    for (int mi = 0; mi < 2; ++mi)
#pragma unroll
        for (int ni = 0; ni < 2; ++ni) acc[mi][ni] = (f32x4){0.f,0.f,0.f,0.f};

    bf16x8 aC[2], bC[2];
    aC[0] = *(const bf16x8*)(A0 + k0);
    aC[1] = *(const bf16x8*)(A1 + k0);
    bC[0] = *(const bf16x8*)(B0 + k0);
    bC[1] = *(const bf16x8*)(B1 + k0);

#pragma unroll
    for (int kk = 0; kk < 8; ++kk) {
        bf16x8 aN[2], bN[2];
        if (kk < 7) {
            const int ko = k0 + (kk + 1) * 32;
            aN[0] = *(const bf16x8*)(A0 + ko);
            aN[1] = *(const bf16x8*)(A1 + ko);
            bN[0] = *(const bf16x8*)(B0 + ko);
            bN[1] = *(const bf16x8*)(B1 + ko);
        }
        acc[0][0] = MFMA16(aC[0], bC[0], acc[0][0]);
        acc[0][1] = MFMA16(aC[0], bC[1], acc[0][1]);
        acc[1][0] = MFMA16(aC[1], bC[0], acc[1][0]);
        acc[1][1] = MFMA16(aC[1], bC[1], acc[1][1]);
        aC[0] = aN[0]; aC[1] = aN[1]; bC[0] = bN[0]; bC[1] = bN[1];
    }

    float* Gp = Gpart + ((size_t)kc * B_ + b) * 65536;
#pragma unroll
    for (int mi = 0; mi < 2; ++mi)
#pragma unroll
        for (int ni = 0; ni < 2; ++ni)
#pragma unroll
            for (int r = 0; r < 4; ++r)
                Gp[(tm + wm + mi * 16 + q * 4 + r) * 256 + tn + wn + ni * 16 + r16]
                    = acc[mi][ni][r];
}

// -------------------------------------------------------------------------
// Kernel 3: reduce split-K partials, scale 1/64, to bf16.
// -------------------------------------------------------------------------
__global__ __launch_bounds__(256) void reduce_g_kernel(
    const float* __restrict__ Gpart,
    unsigned short* __restrict__ Gsum)
{
    const int idx4 = blockIdx.x * 256 + threadIdx.x;
    const size_t base = (size_t)idx4 * 4;
    f32x4 s = (f32x4){0.f,0.f,0.f,0.f};
#pragma unroll
    for (int kc = 0; kc < 8; ++kc) {
        f32x4 v = *(const f32x4*)(Gpart + (size_t)kc * 262144 + base);
        s.x += v.x; s.y += v.y; s.z += v.z; s.w += v.w;
    }
    const float sc = 1.0f / 64.0f;
    ushort4 o;
    o.x = (unsigned short)f2bf(s.x * sc);
    o.y = (unsigned short)f2bf(s.y * sc);
    o.z = (unsigned short)f2bf(s.z * sc);
    o.w = (unsigned short)f2bf(s.w * sc);
    *(ushort4*)(Gsum + base) = o;
}

// -------------------------------------------------------------------------
// Kernel 4: zgemm.  Zt_b[cq][h*256+c'] = sum_{c''} Qt[(h,cq)][c'']*Gs_b[c'][c'']
// 64x64 tiles, grid (16,8,4)=512 blocks.  Double-buffered K-loop.
// -------------------------------------------------------------------------
__global__ __launch_bounds__(256) void zgemm_kernel(
    const unsigned short* __restrict__ Qt,
    const unsigned short* __restrict__ Gsum,
    unsigned short* __restrict__ Zt)
{
    const int t = blockIdx.x;   // 0..15
    const int h = blockIdx.y;
    const int b = blockIdx.z;
    const int tid = threadIdx.x;
    const int w = tid >> 6, L = tid & 63;
    const int r16 = L & 15, q = L >> 4;
    const int tm = (t >> 2) * 64;
    const int tn = (t & 3) * 64;
    const int wm = (w >> 1) * 32, wn = (w & 1) * 32;

    const unsigned short* Qh = Qt + (size_t)h * 65536;
    const unsigned short* Gb = Gsum + (size_t)b * 65536;
    const unsigned short* A0 = Qh + (size_t)(tm + wm + r16) * 256;
    const unsigned short* A1 = A0 + 16 * 256;
    const unsigned short* B0 = Gb + (size_t)(tn + wn + r16) * 256;
    const unsigned short* B1 = B0 + 16 * 256;
    const int k0 = q * 8;

    f32x4 acc[2][2];
#pragma unroll
    for (int mi = 0; mi < 2; ++mi)
#pragma unroll
        for (int ni = 0; ni < 2; ++ni) acc[mi][ni] = (f32x4){0.f,0.f,0.f,0.f};

    bf16x8 aC[2], bC[2];
    aC[0] = *(const bf16x8*)(A0 + k0);
    aC[1] = *(const bf16x8*)(A1 + k0);
    bC[0] = *(const bf16x8*)(B0 + k0);
    bC[1] = *(const bf16x8*)(B1 + k0);

#pragma unroll
    for (int kk = 0; kk < 8; ++kk) {
        bf16x8 aN[2], bN[2];
        if (kk < 7) {
            const int ko = k0 + (kk + 1) * 32;
            aN[0] = *(const bf16x8*)(A0 + ko);
            aN[1] = *(const bf16x8*)(A1 + ko);
            bN[0] = *(const bf16x8*)(B0 + ko);
            bN[1] = *(const bf16x8*)(B1 + ko);
        }
        acc[0][0] = MFMA16(aC[0], bC[0], acc[0][0]);
        acc[0][1] = MFMA16(aC[0], bC[1], acc[0][1]);
        acc[1][0] = MFMA16(aC[1], bC[0], acc[1][0]);
        acc[1][1] = MFMA16(aC[1], bC[1], acc[1][1]);
        aC[0] = aN[0]; aC[1] = aN[1]; bC[0] = bN[0]; bC[1] = bN[1];
    }

    unsigned short* Zb = Zt + (size_t)b * 256 * 2048;
#pragma unroll
    for (int mi = 0; mi < 2; ++mi)
#pragma unroll
        for (int ni = 0; ni < 2; ++ni)
#pragma unroll
            for (int r = 0; r < 4; ++r) {
                const int m = tm + wm + mi * 16 + q * 4 + r;       // cq
                const int n = tn + wn + ni * 16 + r16;             // c'
                Zb[(size_t)m * 2048 + h * 256 + n] = (unsigned short)f2bf(acc[mi][ni][r]);
            }
}

// -------------------------------------------------------------------------
// Kernel 5: ngemm split-K.  Npart[sk][b][c][cq] = sum_{k chunk} P[c][k]*Zt_b[cq][k]
// 64x64 tiles, K=2048 split 4x512, grid (16,4,4)=256 blocks.  Double-buffered.
// -------------------------------------------------------------------------
__global__ __launch_bounds__(256) void ngemm_kernel(
    const unsigned short* __restrict__ P,
    const unsigned short* __restrict__ Zt,
    float* __restrict__ Npart)
{
    const int t = blockIdx.x;   // 0..15
    const int sk = blockIdx.y;
    const int b = blockIdx.z;
    const int tid = threadIdx.x;
    const int w = tid >> 6, L = tid & 63;
    const int r16 = L & 15, q = L >> 4;
    const int tm = (t >> 2) * 64;
    const int tn = (t & 3) * 64;
    const int wm = (w >> 1) * 32, wn = (w & 1) * 32;

    const unsigned short* Zb = Zt + (size_t)b * 256 * 2048;
    const unsigned short* A0 = P  + (size_t)(tm + wm + r16) * 2048;
    const unsigned short* A1 = A0 + 16 * 2048;
    const unsigned short* B0 = Zb + (size_t)(tn + wn + r16) * 2048;
    const unsigned short* B1 = B0 + 16 * 2048;
    const int k0 = sk * 512 + q * 8;

    f32x4 acc[2][2];
#pragma unroll
    for (int mi = 0; mi < 2; ++mi)
#pragma unroll
        for (int ni = 0; ni < 2; ++ni) acc[mi][ni] = (f32x4){0.f,0.f,0.f,0.f};

    bf16x8 aC[2], bC[2];
    aC[0] = *(const bf16x8*)(A0 + k0);
    aC[1] = *(const bf16x8*)(A1 + k0);
    bC[0] = *(const bf16x8*)(B0 + k0);
    bC[1] = *(const bf16x8*)(B1 + k0);

#pragma unroll
    for (int kk = 0; kk < 16; ++kk) {
        bf16x8 aN[2], bN[2];
        if (kk < 15) {
            const int ko = k0 + (kk + 1) * 32;
            aN[0] = *(const bf16x8*)(A0 + ko);
            aN[1] = *(const bf16x8*)(A1 + ko);
            bN[0] = *(const bf16x8*)(B0 + ko);
            bN[1] = *(const bf16x8*)(B1 + ko);
        }
        acc[0][0] = MFMA16(aC[0], bC[0], acc[0][0]);
        acc[0][1] = MFMA16(aC[0], bC[1], acc[0][1]);
        acc[1][0] = MFMA16(aC[1], bC[0], acc[1][0]);
        acc[1][1] = MFMA16(aC[1], bC[1], acc[1][1]);
        aC[0] = aN[0]; aC[1] = aN[1]; bC[0] = bN[0]; bC[1] = bN[1];
    }

    float* Np = Npart + ((size_t)sk * B_ + b) * 65536;
#pragma unroll
    for (int mi = 0; mi < 2; ++mi)
#pragma unroll
        for (int ni = 0; ni < 2; ++ni)
#pragma unroll
            for (int r = 0; r < 4; ++r)
                Np[(tm + wm + mi * 16 + q * 4 + r) * 256 + tn + wn + ni * 16 + r16]
                    = acc[mi][ni][r];
}

// -------------------------------------------------------------------------
// Kernel 6: reduce N partials -> bf16.
// -------------------------------------------------------------------------
__global__ __launch_bounds__(256) void reduce_n_kernel(
    const float* __restrict__ Npart,
    unsigned short* __restrict__ Nbf)
{
    const int idx4 = blockIdx.x * 256 + threadIdx.x;
    const size_t base = (size_t)idx4 * 4;
    f32x4 s = (f32x4){0.f,0.f,0.f,0.f};
#pragma unroll
    for (int sk = 0; sk < 4; ++sk) {
        f32x4 v = *(const f32x4*)(Npart + (size_t)sk * 262144 + base);
        s.x += v.x; s.y += v.y; s.z += v.z; s.w += v.w;
    }
    ushort4 o;
    o.x = (unsigned short)f2bf(s.x);
    o.y = (unsigned short)f2bf(s.y);
    o.z = (unsigned short)f2bf(s.z);
    o.w = (unsigned short)f2bf(s.w);
    *(ushort4*)(Nbf + base) = o;
}

// -------------------------------------------------------------------------
// Kernel 7: final.  out[b][c][n] = g*sum_cq Nbf[b][c][cq]*xqt[b][n][cq] + x_q[b][c][n]
// 64x64 tiles, grid (32,4,4)=512 blocks.  Double-buffered K-loop.
// -------------------------------------------------------------------------
__global__ __launch_bounds__(256) void final_kernel(
    const unsigned short* __restrict__ Nbf,
    const unsigned short* __restrict__ xqt_bf,
    const float* __restrict__ x_q,
    const float* __restrict__ gamma,
    float* __restrict__ out)
{
    const int nblk = blockIdx.x * 64;
    const int cblk = blockIdx.y * 64;
    const int b    = blockIdx.z;
    const int tid  = threadIdx.x;
    const int w = tid >> 6, L = tid & 63;
    const int r16 = L & 15, q = L >> 4;
    const int wc = (w >> 1) * 32;
    const int wn = (w & 1) * 32;

    const unsigned short* Nb = Nbf + (size_t)b * 65536;
    const unsigned short* Xq = xqt_bf + (size_t)b * NQ_ * CQ_;
    const float* Xb = x_q + (size_t)b * CQ_ * NQ_;
    const float g = gamma[0];

    const unsigned short* A0 = Nb + (size_t)(cblk + wc + r16) * 256;
    const unsigned short* A1 = A0 + 16 * 256;
    const unsigned short* B0 = Xq + (size_t)(nblk + wn + r16) * 256;
    const unsigned short* B1 = B0 + 16 * 256;
    const int k0 = q * 8;

    f32x4 acc[2][2];
#pragma unroll
    for (int mi = 0; mi < 2; ++mi)
#pragma unroll
        for (int ni = 0; ni < 2; ++ni) acc[mi][ni] = (f32x4){0.f,0.f,0.f,0.f};

    bf16x8 aC[2], bC[2];
    aC[0] = *(const bf16x8*)(A0 + k0);
    aC[1] = *(const bf16x8*)(A1 + k0);
    bC[0] = *(const bf16x8*)(B0 + k0);
    bC[1] = *(const bf16x8*)(B1 + k0);

#pragma unroll
    for (int kk = 0; kk < 8; ++kk) {
        bf16x8 aN[2], bN[2];
        if (kk < 7) {
            const int ko = k0 + (kk + 1) * 32;
            aN[0] = *(const bf16x8*)(A0 + ko);
            aN[1] = *(const bf16x8*)(A1 + ko);
            bN[0] = *(const bf16x8*)(B0 + ko);
            bN[1] = *(const bf16x8*)(B1 + ko);
        }
        acc[0][0] = MFMA16(aC[0], bC[0], acc[0][0]);
        acc[0][1] = MFMA16(aC[0], bC[1], acc[0][1]);
        acc[1][0] = MFMA16(aC[1], bC[0], acc[1][0]);
        acc[1][1] = MFMA16(aC[1], bC[1], acc[1][1]);
        aC[0] = aN[0]; aC[1] = aN[1]; bC[0] = bN[0]; bC[1] = bN[1];
    }

#pragma unroll
    for (int mi = 0; mi < 2; ++mi)
#pragma unroll
        for (int ni = 0; ni < 2; ++ni)
#pragma unroll
            for (int r = 0; r < 4; ++r) {
                const int c = cblk + wc + mi * 16 + q * 4 + r;
                const int n = nblk + wn + ni * 16 + r16;
                const size_t idx = ((size_t)b * CQ_ + c) * NQ_ + n;
                out[idx] = g * acc[mi][ni][r] + Xb[(size_t)c * NQ_ + n];
            }
}

// -------------------------------------------------------------------------
extern "C" void kernel_launch(void* const* d_in, const int* in_sizes, int n_in,
                              void* d_out, int out_size, void* d_ws, size_t ws_size,
                              hipStream_t stream) {
    const float* x_q   = (const float*)d_in[0];
    const float* x_kv  = (const float*)d_in[1];
    const float* Wq    = (const float*)d_in[2];
    const float* Wk    = (const float*)d_in[3];
    const float* Wv    = (const float*)d_in[4];
    const float* Wo    = (const float*)d_in[5];
    const float* gamma = (const float*)d_in[6];
    float* out = (float*)d_out;

    char* ws = (char*)d_ws;
    // ws layout (bytes):
    //   xkv_bf bf16 [4][256][2048]        0 ..  4194304
    //   xqt_bf bf16 [4][2048][256]  4194304 ..  8388608
    //   Gpart  f32  [8][4][256][256]8388608 .. 16777216   (aliased by Npart)
    //   Npart  f32  [4][4][256][256]8388608 .. 12582912   (after reduce_g done)
    //   Gsum   bf16 [4][256][256]  16777216 .. 17301504
    //   P      bf16 [256][2048]    17301504 .. 18350080
    //   Qt     bf16 [2048][256]    18350080 .. 19398656
    //   Zt     bf16 [4][256][2048] 19398656 .. 23592960
    //   Nbf    bf16 [4][256][256]  23592960 .. 24117248
    unsigned short* xkv_bf = (unsigned short*)(ws);
    unsigned short* xqt_bf = (unsigned short*)(ws + 4194304);
    float*          Gpart  = (float*)(ws + 8388608);
    float*          Npart  = (float*)(ws + 8388608);
    unsigned short* Gsum   = (unsigned short*)(ws + 16777216);
    unsigned short* P      = (unsigned short*)(ws + 17301504);
    unsigned short* Qt     = (unsigned short*)(ws + 18350080);
    unsigned short* Zt     = (unsigned short*)(ws + 19398656);
    unsigned short* Nbf    = (unsigned short*)(ws + 23592960);

    prep_pq_kernel<<<dim3(1664), 256, 0, stream>>>(x_kv, x_q, Wq, Wk, Wv, Wo,
                                                   xkv_bf, xqt_bf, P, Qt);
    gram_kernel<<<dim3(8, 16, 4), 256, 0, stream>>>(xkv_bf, Gpart);
    reduce_g_kernel<<<dim3(256), 256, 0, stream>>>(Gpart, Gsum);
    zgemm_kernel<<<dim3(16, 8, 4), 256, 0, stream>>>(Qt, Gsum, Zt);
    ngemm_kernel<<<dim3(16, 4, 4), 256, 0, stream>>>(P, Zt, Npart);
    reduce_n_kernel<<<dim3(256), 256, 0, stream>>>(Npart, Nbf);
    final_kernel<<<dim3(32, 4, 4), 256, 0, stream>>>(Nbf, xqt_bf, x_q, gamma, out);
}